// Round 12
// baseline (410.231 us; speedup 1.0000x reference)
//
#include <hip/hip_runtime.h>
#include <hip/hip_fp16.h>

#define BN_EPS 1e-5f

typedef unsigned int uint32;
typedef __attribute__((ext_vector_type(8))) _Float16 f16x8;
typedef __attribute__((ext_vector_type(4))) float f32x4;

union H2U { __half2 h; uint32 u; };

__device__ __forceinline__ __half2 u2h(uint32 u) { H2U c; c.u = u; return c.h; }
__device__ __forceinline__ uint32 h2u(__half2 h) { H2U c; c.h = h; return c.u; }
__device__ __forceinline__ uint32 pack2h(float a, float b) {
    return h2u(__halves2half2(__float2half_rn(a), __float2half_rn(b)));
}
__device__ __forceinline__ float h2lo(uint32 u) {
    return __half2float(__ushort_as_half((unsigned short)(u & 0xffffu)));
}
__device__ __forceinline__ float h2hi(uint32 u) {
    return __half2float(__ushort_as_half((unsigned short)(u >> 16)));
}

// ---------------- fused: bucket scatter (blocks 0-255) + fp32->fp16 convert (blocks 256+) ----

__global__ void __launch_bounds__(256) k_prep_scatter(const float4* __restrict__ x4, int nx4,
                                                      const float4* __restrict__ w4, int nw4,
                                                      uint2* __restrict__ xh4, uint2* __restrict__ wh4,
                                                      const int* __restrict__ ei, int E, int NB,
                                                      int CAP, int* __restrict__ bfill,
                                                      uint32* __restrict__ bpack) {
    int t = threadIdx.x;
    if (blockIdx.x < 256) {
        __shared__ int h[4][1024];
        int wave = t >> 6;
        int c0 = (int)((long long)blockIdx.x * E / 256);
        int c1 = (int)((long long)(blockIdx.x + 1) * E / 256);
        for (int i = t; i < 4 * 1024; i += 256) h[i >> 10][i & 1023] = 0;
        __syncthreads();
        for (int e = c0 + t; e < c1; e += 256)
            atomicAdd(&h[wave][ei[E + e] >> 8], 1);
        __syncthreads();
        for (int i = t; i < NB; i += 256) {
            int n0 = h[0][i], n1 = h[1][i], n2 = h[2][i], n3 = h[3][i];
            int tot = n0 + n1 + n2 + n3;
            if (tot > 0) {
                int base = i * CAP + atomicAdd(&bfill[i], tot);
                h[0][i] = base;
                h[1][i] = base + n0;
                h[2][i] = base + n0 + n1;
                h[3][i] = base + n0 + n1 + n2;
            }
        }
        __syncthreads();
        for (int e = c0 + t; e < c1; e += 256) {
            int s = ei[e];
            int d = ei[E + e];
            int b = d >> 8;
            int pos = atomicAdd(&h[wave][b], 1);
            bpack[pos] = ((uint32)(d & 255) << 24) | (uint32)s;
        }
    } else {
        int nb = gridDim.x - 256;
        int idx = (blockIdx.x - 256) * 256 + t;
        int stride = nb * 256;
        for (int i = idx; i < nx4; i += stride) {
            float4 v = x4[i];
            xh4[i] = make_uint2(pack2h(v.x, v.y), pack2h(v.z, v.w));
        }
        for (int i = idx; i < nw4; i += stride) {
            float4 v = w4[i];
            wh4[i] = make_uint2(pack2h(v.x, v.y), pack2h(v.z, v.w));
        }
    }
}

// ---------------- per-bucket CSR ----------------

__global__ void __launch_bounds__(256) k_csr(const uint32* __restrict__ bpack,
                                             const int* __restrict__ bfill, int CAP,
                                             int N,
                                             int* __restrict__ rowptr,
                                             int* __restrict__ rowcnt,
                                             uint32* __restrict__ dpk,
                                             int* __restrict__ col) {
    __shared__ int h[4][256], s[256], cur[4][256];
    int b = blockIdx.x;
    int t = threadIdx.x;
    int wave = t >> 6;
    int e0 = b * CAP, e1 = e0 + bfill[b];
    h[0][t] = 0; h[1][t] = 0; h[2][t] = 0; h[3][t] = 0;
    __syncthreads();
    for (int e = e0 + t; e < e1; e += 256)
        atomicAdd(&h[wave][bpack[e] >> 24], 1);
    __syncthreads();
    int n0 = h[0][t], n1 = h[1][t], n2 = h[2][t], n3 = h[3][t];
    int cnt = n0 + n1 + n2 + n3;
    s[t] = cnt;
    __syncthreads();
    for (int off = 1; off < 256; off <<= 1) {
        int add = (t >= off) ? s[t - off] : 0;
        __syncthreads();
        s[t] += add;
        __syncthreads();
    }
    int excl = s[t] - cnt;
    int node = (b << 8) + t;
    if (node < N) {
        rowptr[node] = e0 + excl;
        rowcnt[node] = cnt;
        float dv = rsqrtf((float)(cnt + 1));
        dpk[node] = pack2h(dv, dv);
    }
    cur[0][t] = e0 + excl;
    cur[1][t] = e0 + excl + n0;
    cur[2][t] = e0 + excl + n0 + n1;
    cur[3][t] = e0 + excl + n0 + n1 + n2;
    __syncthreads();
    for (int e = e0 + t; e < e1; e += 256) {
        uint32 p = bpack[e];
        int pos = atomicAdd(&cur[wave][p >> 24], 1);
        col[pos] = (int)(p & 0xffffffu);
    }
}

// ---------------- aggregation: wave-per-node, ZERO LDS (latency-bound, max occupancy) ----

#define EDGE_FMA(vv, ww)                                   \
    acc0 = __hfma2(u2h((vv).x), u2h(ww), acc0);            \
    acc1 = __hfma2(u2h((vv).y), u2h(ww), acc1);            \
    acc2 = __hfma2(u2h((vv).z), u2h(ww), acc2);            \
    acc3 = __hfma2(u2h((vv).w), u2h(ww), acc3);

__global__ void __launch_bounds__(256) k_agg(const uint32* __restrict__ xh,
                                             const int* __restrict__ rowptr,
                                             const int* __restrict__ rowcnt,
                                             const int* __restrict__ col,
                                             const uint32* __restrict__ dpk,
                                             uint32* __restrict__ aggh, int N) {
    int wid = blockIdx.x * 4 + (threadIdx.x >> 6);
    if (wid >= N) return;
    int lane = threadIdx.x & 63;
    int g = lane >> 4, c = lane & 15;

    __half2 z = __float2half2_rn(0.f);
    __half2 acc0 = z, acc1 = z, acc2 = z, acc3 = z;

    int e0 = rowptr[wid];
    int e1 = e0 + rowcnt[wid];
    int e = e0;
    for (; e + 16 <= e1; e += 16) {
        int i0 = e + g, i1 = e + 4 + g, i2 = e + 8 + g, i3 = e + 12 + g;
        int s0 = col[i0], s1 = col[i1], s2 = col[i2], s3 = col[i3];
        uint32 w0 = dpk[s0], w1 = dpk[s1], w2 = dpk[s2], w3 = dpk[s3];
        uint4 v0 = *(const uint4*)&xh[(size_t)s0 * 64 + c * 4];
        uint4 v1 = *(const uint4*)&xh[(size_t)s1 * 64 + c * 4];
        uint4 v2 = *(const uint4*)&xh[(size_t)s2 * 64 + c * 4];
        uint4 v3 = *(const uint4*)&xh[(size_t)s3 * 64 + c * 4];
        EDGE_FMA(v0, w0); EDGE_FMA(v1, w1); EDGE_FMA(v2, w2); EDGE_FMA(v3, w3);
    }
    if (e < e1) {
        int i0 = e + g, i1 = e + 4 + g, i2 = e + 8 + g, i3 = e + 12 + g;
        int s0 = 0, s1 = 0, s2 = 0, s3 = 0;
        uint32 w0 = 0, w1 = 0, w2 = 0, w3 = 0;
        if (i0 < e1) { s0 = col[i0]; w0 = dpk[s0]; }
        if (i1 < e1) { s1 = col[i1]; w1 = dpk[s1]; }
        if (i2 < e1) { s2 = col[i2]; w2 = dpk[s2]; }
        if (i3 < e1) { s3 = col[i3]; w3 = dpk[s3]; }
        uint4 v0 = *(const uint4*)&xh[(size_t)s0 * 64 + c * 4];
        uint4 v1 = *(const uint4*)&xh[(size_t)s1 * 64 + c * 4];
        uint4 v2 = *(const uint4*)&xh[(size_t)s2 * 64 + c * 4];
        uint4 v3 = *(const uint4*)&xh[(size_t)s3 * 64 + c * 4];
        EDGE_FMA(v0, w0); EDGE_FMA(v1, w1); EDGE_FMA(v2, w2); EDGE_FMA(v3, w3);
    }
    uint32 u;
    u = __shfl_xor(h2u(acc0), 16); acc0 = __hadd2(acc0, u2h(u));
    u = __shfl_xor(h2u(acc0), 32); acc0 = __hadd2(acc0, u2h(u));
    u = __shfl_xor(h2u(acc1), 16); acc1 = __hadd2(acc1, u2h(u));
    u = __shfl_xor(h2u(acc1), 32); acc1 = __hadd2(acc1, u2h(u));
    u = __shfl_xor(h2u(acc2), 16); acc2 = __hadd2(acc2, u2h(u));
    u = __shfl_xor(h2u(acc2), 32); acc2 = __hadd2(acc2, u2h(u));
    u = __shfl_xor(h2u(acc3), 16); acc3 = __hadd2(acc3, u2h(u));
    u = __shfl_xor(h2u(acc3), 32); acc3 = __hadd2(acc3, u2h(u));

    if (g == 0) {
        float di = h2lo(dpk[wid]);
        uint4 sv = *(const uint4*)&xh[(size_t)wid * 64 + c * 4];
        uint4 o;
        o.x = pack2h(di * (di * h2lo(sv.x) + __low2float(acc0)),
                     di * (di * h2hi(sv.x) + __high2float(acc0)));
        o.y = pack2h(di * (di * h2lo(sv.y) + __low2float(acc1)),
                     di * (di * h2hi(sv.y) + __high2float(acc1)));
        o.z = pack2h(di * (di * h2lo(sv.z) + __low2float(acc2)),
                     di * (di * h2hi(sv.z) + __high2float(acc2)));
        o.w = pack2h(di * (di * h2lo(sv.w) + __low2float(acc3)),
                     di * (di * h2hi(sv.w) + __high2float(acc3)));
        *(uint4*)&aggh[(size_t)wid * 64 + c * 4] = o;
    }
}

// ---------------- fused GEMM: stats (acc kept in regs) -> last-block BN params -> apply ----
// grid MUST be 512 (= 2 blocks/CU x 256 CU, enforced co-resident by __launch_bounds__(256,2))

#define STAGE_W()                                                            \
    for (int m = threadIdx.x; m < 2048; m += 256) {                          \
        int row = m >> 4, cc = m & 15;                                       \
        uint4 v = *(const uint4*)&Wh[row * 128 + cc * 8];                    \
        *(uint4*)((char*)wlds + row * 256 + ((cc * 16) ^ ((row & 7) << 4))) = v; \
    }

#define MFMA_TILE(accA, tile)                                                \
    {                                                                        \
        int arow = (tile) * 64 + wave * 16 + lrow;                           \
        bool avalid = arow < N;                                              \
        _Pragma("unroll")                                                    \
        for (int kc = 0; kc < 4; ++kc) {                                     \
            f16x8 a;                                                         \
            if (avalid) a = *(const f16x8*)&Ah[(size_t)arow * 128 + kc * 32 + g * 8]; \
            else        a = (f16x8){0, 0, 0, 0, 0, 0, 0, 0};                 \
            _Pragma("unroll")                                                \
            for (int ct = 0; ct < 8; ++ct) {                                 \
                int row = ct * 16 + lrow;                                    \
                const f16x8 bfr = *(const f16x8*)((const char*)wlds + row * 256 \
                                   + ((kc * 64 + g * 16) ^ ((row & 7) << 4))); \
                accA[ct] = __builtin_amdgcn_mfma_f32_16x16x32_f16(a, bfr, accA[ct], 0, 0, 0); \
            }                                                                \
        }                                                                    \
    }

__global__ void __launch_bounds__(256, 2) k_gemm_fused(const _Float16* __restrict__ Ah,
                                                       const _Float16* __restrict__ Wh,
                                                       const float* __restrict__ bias,
                                                       const float* __restrict__ gamma,
                                                       const float* __restrict__ beta,
                                                       const uint32* __restrict__ xh,
                                                       int N, int ntiles, float invN,
                                                       float* __restrict__ partials,
                                                       float* __restrict__ ss,
                                                       int* __restrict__ counter,
                                                       int* __restrict__ flag,
                                                       float* __restrict__ out) {
    __shared__ uint32 wlds[8192];   // 32 KB W, XOR-swizzled
    __shared__ float red[1024];
    __shared__ int sh_last;
    STAGE_W();
    __syncthreads();

    int t = threadIdx.x;
    int wave = t >> 6, lane = t & 63;
    int lrow = lane & 15, g = lane >> 4;
    int G = gridDim.x;

    float bv[8];
    #pragma unroll
    for (int ct = 0; ct < 8; ++ct) bv[ct] = bias[ct * 16 + lrow];

    float s[8], sq[8];
    #pragma unroll
    for (int ct = 0; ct < 8; ++ct) { s[ct] = 0.f; sq[ct] = 0.f; }

    // ---- phase 1: stats MFMA, accumulators retained in registers (4 tiles max) ----
    f32x4 acc[4][8];
    #pragma unroll
    for (int tt = 0; tt < 4; ++tt) {
        #pragma unroll
        for (int ct = 0; ct < 8; ++ct) acc[tt][ct] = (f32x4){0.f, 0.f, 0.f, 0.f};
        int tile = blockIdx.x + tt * G;
        if (tile < ntiles) {
            MFMA_TILE(acc[tt], tile);
            int orow0 = tile * 64 + wave * 16 + g * 4;
            #pragma unroll
            for (int ct = 0; ct < 8; ++ct) {
                #pragma unroll
                for (int rr = 0; rr < 4; ++rr) {
                    if (orow0 + rr < N) {
                        float o = acc[tt][ct][rr] + bv[ct];
                        s[ct] += o; sq[ct] += o * o;
                    }
                }
            }
        }
    }

    // ---- block partials ----
    #pragma unroll
    for (int ct = 0; ct < 8; ++ct) {
        s[ct] += __shfl_xor(s[ct], 16); sq[ct] += __shfl_xor(sq[ct], 16);
        s[ct] += __shfl_xor(s[ct], 32); sq[ct] += __shfl_xor(sq[ct], 32);
    }
    if (lane < 16) {
        #pragma unroll
        for (int ct = 0; ct < 8; ++ct) {
            int colI = ct * 16 + lrow;
            red[wave * 256 + colI] = s[ct];
            red[wave * 256 + 128 + colI] = sq[ct];
        }
    }
    __syncthreads();
    if (t < 256)
        partials[blockIdx.x * 256 + t] = red[t] + red[256 + t] + red[512 + t] + red[768 + t];

    // ---- last-finishing block computes BN params; others wait on flag ----
    __threadfence();
    __syncthreads();
    if (t == 0) {
        int prev = __hip_atomic_fetch_add(counter, 1, __ATOMIC_ACQ_REL, __HIP_MEMORY_SCOPE_AGENT);
        sh_last = (prev == G - 1) ? 1 : 0;
    }
    __syncthreads();
    if (sh_last) {
        float v0 = 0.f, v1 = 0.f, v2 = 0.f, v3 = 0.f;
        for (int b = 0; b < G; b += 4) {
            v0 += partials[(b + 0) * 256 + t];
            v1 += partials[(b + 1) * 256 + t];
            v2 += partials[(b + 2) * 256 + t];
            v3 += partials[(b + 3) * 256 + t];
        }
        red[t] = (v0 + v1) + (v2 + v3);
        __syncthreads();
        if (t < 128) {
            float mean = red[t] * invN;
            float var = red[128 + t] * invN - mean * mean;
            float sc = gamma[t] * rsqrtf(var + BN_EPS);
            ss[t] = sc;
            ss[128 + t] = beta[t] - mean * sc;
        }
        __threadfence();
        __syncthreads();
        if (t == 0) __hip_atomic_store(flag, 1, __ATOMIC_RELEASE, __HIP_MEMORY_SCOPE_AGENT);
    } else {
        if (t == 0) {
            while (__hip_atomic_load(flag, __ATOMIC_ACQUIRE, __HIP_MEMORY_SCOPE_AGENT) == 0)
                __builtin_amdgcn_s_sleep(8);
        }
        __syncthreads();
    }

    // ---- phase 2: apply from retained accumulators ----
    float scv[8], shv[8];
    #pragma unroll
    for (int ct = 0; ct < 8; ++ct) {
        int colI = ct * 16 + lrow;
        scv[ct] = ss[colI]; shv[ct] = ss[128 + colI];
    }
    #pragma unroll
    for (int tt = 0; tt < 4; ++tt) {
        int tile = blockIdx.x + tt * G;
        if (tile < ntiles) {
            int orow0 = tile * 64 + wave * 16 + g * 4;
            #pragma unroll
            for (int ct = 0; ct < 8; ++ct) {
                int ocol = ct * 16 + lrow;
                #pragma unroll
                for (int rr = 0; rr < 4; ++rr) {
                    int r = orow0 + rr;
                    if (r < N) {
                        float pre = acc[tt][ct][rr] + bv[ct];
                        float o = fmaxf(pre * scv[ct] + shv[ct], 0.f);
                        uint32 xv = xh[(size_t)r * 64 + (ocol >> 1)];
                        float xr = (ocol & 1) ? h2hi(xv) : h2lo(xv);
                        out[(size_t)r * 128 + ocol] = o + xr;
                    }
                }
            }
        }
    }
}

// ---------------- launcher ----------------

extern "C" void kernel_launch(void* const* d_in, const int* in_sizes, int n_in,
                              void* d_out, int out_size, void* d_ws, size_t ws_size,
                              hipStream_t stream) {
    const float* x     = (const float*)d_in[0];
    const int*   ei    = (const int*)d_in[1];
    const float* W     = (const float*)d_in[2];
    const float* bias  = (const float*)d_in[3];
    const float* gamma = (const float*)d_in[4];
    const float* beta  = (const float*)d_in[5];
    float* out = (float*)d_out;

    const int D = 128;
    int N = in_sizes[0] / D;           // requires N <= 256*1024 and ntiles <= 4*512
    int E = in_sizes[1] / 2;
    int NB = (N + 255) >> 8;           // 256-node buckets
    int CAP = ((E + NB - 1) / NB + 1024 + 63) & ~63;

    const int GFUSED = 512;            // exact 2-blocks/CU co-resident capacity

    char* ws = (char*)d_ws;
    size_t off = 0;
    auto alloc = [&](size_t bytes) -> void* {
        void* p = ws + off;
        off += (bytes + 255) & ~(size_t)255;
        return p;
    };
    uint32* xh   = (uint32*)alloc((size_t)N * 64 * sizeof(uint32));   // x fp16
    uint32* aggh = (uint32*)alloc((size_t)N * 64 * sizeof(uint32));   // agg fp16
    uint32* bpack= (uint32*)alloc((size_t)NB * CAP * sizeof(uint32));
    int* col     = (int*)alloc((size_t)NB * CAP * sizeof(int));
    _Float16* Wh = (_Float16*)alloc((size_t)D * D * sizeof(_Float16));
    int* rowptr  = (int*)alloc((size_t)N * sizeof(int));
    int* rowcnt  = (int*)alloc((size_t)N * sizeof(int));
    uint32* dpk  = (uint32*)alloc((size_t)N * sizeof(uint32));        // {dinv,dinv} fp16
    float* ss    = (float*)alloc(256 * sizeof(float));
    float* partials = (float*)alloc((size_t)GFUSED * 256 * sizeof(float));
    int* bfill   = (int*)alloc(1024 * sizeof(int));   // zeroed每 launch
    int* ctl     = (int*)alloc(64 * sizeof(int));     // [0]=counter [1]=flag (contiguous with bfill)

    hipMemsetAsync(bfill, 0, 1024 * sizeof(int) + 64 * sizeof(int), stream);

    k_prep_scatter<<<2048, 256, 0, stream>>>((const float4*)x, N * 32,
                                             (const float4*)W, D * D / 4,
                                             (uint2*)xh, (uint2*)Wh,
                                             ei, E, NB, CAP, bfill, bpack);
    k_csr<<<NB, 256, 0, stream>>>(bpack, bfill, CAP, N, rowptr, rowcnt, dpk, col);
    k_agg<<<(N + 3) / 4, 256, 0, stream>>>(xh, rowptr, rowcnt, col, dpk, aggh, N);

    int ntiles = (N + 63) / 64;
    k_gemm_fused<<<GFUSED, 256, 0, stream>>>((const _Float16*)aggh, (const _Float16*)Wh,
                                             bias, gamma, beta, xh,
                                             N, ntiles, 1.0f / (float)N,
                                             partials, ss, &ctl[0], &ctl[1], out);
}

// Round 13
// 179.078 us; speedup vs baseline: 2.2908x; 2.2908x over previous
//
#include <hip/hip_runtime.h>
#include <hip/hip_fp16.h>

#define BN_EPS 1e-5f

typedef unsigned int uint32;
typedef __attribute__((ext_vector_type(8))) _Float16 f16x8;
typedef __attribute__((ext_vector_type(4))) float f32x4;

union H2U { __half2 h; uint32 u; };

__device__ __forceinline__ __half2 u2h(uint32 u) { H2U c; c.u = u; return c.h; }
__device__ __forceinline__ uint32 h2u(__half2 h) { H2U c; c.h = h; return c.u; }
__device__ __forceinline__ uint32 pack2h(float a, float b) {
    return h2u(__halves2half2(__float2half_rn(a), __float2half_rn(b)));
}
__device__ __forceinline__ float h2lo(uint32 u) {
    return __half2float(__ushort_as_half((unsigned short)(u & 0xffffu)));
}
__device__ __forceinline__ float h2hi(uint32 u) {
    return __half2float(__ushort_as_half((unsigned short)(u >> 16)));
}

// ---------------- fused: bucket scatter (blocks 0-255) + fp32->fp16 convert (blocks 256+) ----

__global__ void __launch_bounds__(256) k_prep_scatter(const float4* __restrict__ x4, int nx4,
                                                      const float4* __restrict__ w4, int nw4,
                                                      uint2* __restrict__ xh4, uint2* __restrict__ wh4,
                                                      const int* __restrict__ ei, int E, int NB,
                                                      int CAP, int* __restrict__ bfill,
                                                      uint32* __restrict__ bpack) {
    int t = threadIdx.x;
    if (blockIdx.x < 256) {
        // ---- bucket scatter slice (wave-replicated LDS counters) ----
        __shared__ int h[4][1024];
        int wave = t >> 6;
        int c0 = (int)((long long)blockIdx.x * E / 256);
        int c1 = (int)((long long)(blockIdx.x + 1) * E / 256);
        for (int i = t; i < 4 * 1024; i += 256) h[i >> 10][i & 1023] = 0;
        __syncthreads();
        for (int e = c0 + t; e < c1; e += 256)
            atomicAdd(&h[wave][ei[E + e] >> 8], 1);
        __syncthreads();
        for (int i = t; i < NB; i += 256) {
            int n0 = h[0][i], n1 = h[1][i], n2 = h[2][i], n3 = h[3][i];
            int tot = n0 + n1 + n2 + n3;
            if (tot > 0) {
                int base = i * CAP + atomicAdd(&bfill[i], tot);
                h[0][i] = base;
                h[1][i] = base + n0;
                h[2][i] = base + n0 + n1;
                h[3][i] = base + n0 + n1 + n2;
            }
        }
        __syncthreads();
        for (int e = c0 + t; e < c1; e += 256) {
            int s = ei[e];
            int d = ei[E + e];
            int b = d >> 8;
            int pos = atomicAdd(&h[wave][b], 1);
            bpack[pos] = ((uint32)(d & 255) << 24) | (uint32)s;
        }
    } else {
        // ---- fp32 -> fp16 convert (runs concurrently with scatter) ----
        int nb = gridDim.x - 256;
        int idx = (blockIdx.x - 256) * 256 + t;
        int stride = nb * 256;
        for (int i = idx; i < nx4; i += stride) {
            float4 v = x4[i];
            xh4[i] = make_uint2(pack2h(v.x, v.y), pack2h(v.z, v.w));
        }
        for (int i = idx; i < nw4; i += stride) {
            float4 v = w4[i];
            wh4[i] = make_uint2(pack2h(v.x, v.y), pack2h(v.z, v.w));
        }
    }
}

// ---------------- per-bucket CSR: count, scan, rowptr/rowcnt, dinv(fp16x2), col --------

__global__ void __launch_bounds__(256) k_csr(const uint32* __restrict__ bpack,
                                             const int* __restrict__ bfill, int CAP,
                                             int N,
                                             int* __restrict__ rowptr,
                                             int* __restrict__ rowcnt,
                                             uint32* __restrict__ dpk,
                                             int* __restrict__ col) {
    __shared__ int h[4][256], s[256], cur[4][256];
    int b = blockIdx.x;
    int t = threadIdx.x;
    int wave = t >> 6;
    int e0 = b * CAP, e1 = e0 + bfill[b];
    h[0][t] = 0; h[1][t] = 0; h[2][t] = 0; h[3][t] = 0;
    __syncthreads();
    for (int e = e0 + t; e < e1; e += 256)
        atomicAdd(&h[wave][bpack[e] >> 24], 1);
    __syncthreads();
    int n0 = h[0][t], n1 = h[1][t], n2 = h[2][t], n3 = h[3][t];
    int cnt = n0 + n1 + n2 + n3;
    s[t] = cnt;
    __syncthreads();
    for (int off = 1; off < 256; off <<= 1) {
        int add = (t >= off) ? s[t - off] : 0;
        __syncthreads();
        s[t] += add;
        __syncthreads();
    }
    int excl = s[t] - cnt;
    int node = (b << 8) + t;
    if (node < N) {
        rowptr[node] = e0 + excl;
        rowcnt[node] = cnt;
        float dv = rsqrtf((float)(cnt + 1));
        dpk[node] = pack2h(dv, dv);
    }
    cur[0][t] = e0 + excl;
    cur[1][t] = e0 + excl + n0;
    cur[2][t] = e0 + excl + n0 + n1;
    cur[3][t] = e0 + excl + n0 + n1 + n2;
    __syncthreads();
    for (int e = e0 + t; e < e1; e += 256) {
        uint32 p = bpack[e];
        int pos = atomicAdd(&cur[wave][p >> 24], 1);
        col[pos] = (int)(p & 0xffffffu);
    }
}

// ---------------- aggregation: wave-per-node, 16 edges/iter, 4 gathers in flight --------
// aggx[i] = di*(di*x[i] + sum_j dinv[j]*x[j]) ; ZERO LDS -> max occupancy (latency-bound)
// Measured floor: ~62 us across 4 structures; limited by random-64B-line L2-miss service.

#define EDGE_FMA(vv, ww)                                   \
    acc0 = __hfma2(u2h((vv).x), u2h(ww), acc0);            \
    acc1 = __hfma2(u2h((vv).y), u2h(ww), acc1);            \
    acc2 = __hfma2(u2h((vv).z), u2h(ww), acc2);            \
    acc3 = __hfma2(u2h((vv).w), u2h(ww), acc3);

__global__ void __launch_bounds__(256) k_agg(const uint32* __restrict__ xh,
                                             const int* __restrict__ rowptr,
                                             const int* __restrict__ rowcnt,
                                             const int* __restrict__ col,
                                             const uint32* __restrict__ dpk,
                                             uint32* __restrict__ aggh, int N) {
    int wid = blockIdx.x * 4 + (threadIdx.x >> 6);
    if (wid >= N) return;
    int lane = threadIdx.x & 63;
    int g = lane >> 4, c = lane & 15;

    __half2 z = __float2half2_rn(0.f);
    __half2 acc0 = z, acc1 = z, acc2 = z, acc3 = z;

    int e0 = rowptr[wid];
    int e1 = e0 + rowcnt[wid];
    int e = e0;
    for (; e + 16 <= e1; e += 16) {
        int i0 = e + g, i1 = e + 4 + g, i2 = e + 8 + g, i3 = e + 12 + g;
        int s0 = col[i0], s1 = col[i1], s2 = col[i2], s3 = col[i3];
        uint32 w0 = dpk[s0], w1 = dpk[s1], w2 = dpk[s2], w3 = dpk[s3];
        uint4 v0 = *(const uint4*)&xh[(size_t)s0 * 64 + c * 4];
        uint4 v1 = *(const uint4*)&xh[(size_t)s1 * 64 + c * 4];
        uint4 v2 = *(const uint4*)&xh[(size_t)s2 * 64 + c * 4];
        uint4 v3 = *(const uint4*)&xh[(size_t)s3 * 64 + c * 4];
        EDGE_FMA(v0, w0); EDGE_FMA(v1, w1); EDGE_FMA(v2, w2); EDGE_FMA(v3, w3);
    }
    if (e < e1) {  // masked tail, <=15 edges
        int i0 = e + g, i1 = e + 4 + g, i2 = e + 8 + g, i3 = e + 12 + g;
        int s0 = 0, s1 = 0, s2 = 0, s3 = 0;
        uint32 w0 = 0, w1 = 0, w2 = 0, w3 = 0;
        if (i0 < e1) { s0 = col[i0]; w0 = dpk[s0]; }
        if (i1 < e1) { s1 = col[i1]; w1 = dpk[s1]; }
        if (i2 < e1) { s2 = col[i2]; w2 = dpk[s2]; }
        if (i3 < e1) { s3 = col[i3]; w3 = dpk[s3]; }
        uint4 v0 = *(const uint4*)&xh[(size_t)s0 * 64 + c * 4];
        uint4 v1 = *(const uint4*)&xh[(size_t)s1 * 64 + c * 4];
        uint4 v2 = *(const uint4*)&xh[(size_t)s2 * 64 + c * 4];
        uint4 v3 = *(const uint4*)&xh[(size_t)s3 * 64 + c * 4];
        EDGE_FMA(v0, w0); EDGE_FMA(v1, w1); EDGE_FMA(v2, w2); EDGE_FMA(v3, w3);
    }
    // reduce across the 4 edge-groups (lanes xor 16, 32)
    uint32 u;
    u = __shfl_xor(h2u(acc0), 16); acc0 = __hadd2(acc0, u2h(u));
    u = __shfl_xor(h2u(acc0), 32); acc0 = __hadd2(acc0, u2h(u));
    u = __shfl_xor(h2u(acc1), 16); acc1 = __hadd2(acc1, u2h(u));
    u = __shfl_xor(h2u(acc1), 32); acc1 = __hadd2(acc1, u2h(u));
    u = __shfl_xor(h2u(acc2), 16); acc2 = __hadd2(acc2, u2h(u));
    u = __shfl_xor(h2u(acc2), 32); acc2 = __hadd2(acc2, u2h(u));
    u = __shfl_xor(h2u(acc3), 16); acc3 = __hadd2(acc3, u2h(u));
    u = __shfl_xor(h2u(acc3), 32); acc3 = __hadd2(acc3, u2h(u));

    if (g == 0) {
        float di = h2lo(dpk[wid]);
        uint4 sv = *(const uint4*)&xh[(size_t)wid * 64 + c * 4];
        uint4 o;
        o.x = pack2h(di * (di * h2lo(sv.x) + __low2float(acc0)),
                     di * (di * h2hi(sv.x) + __high2float(acc0)));
        o.y = pack2h(di * (di * h2lo(sv.y) + __low2float(acc1)),
                     di * (di * h2hi(sv.y) + __high2float(acc1)));
        o.z = pack2h(di * (di * h2lo(sv.z) + __low2float(acc2)),
                     di * (di * h2hi(sv.z) + __high2float(acc2)));
        o.w = pack2h(di * (di * h2lo(sv.w) + __low2float(acc3)),
                     di * (di * h2hi(sv.w) + __high2float(acc3)));
        *(uint4*)&aggh[(size_t)wid * 64 + c * 4] = o;
    }
}

// ---------------- persistent MFMA GEMM (fp16), W staged in LDS (XOR-swizzled, 32 KB) ----

#define STAGE_W()                                                            \
    for (int m = threadIdx.x; m < 2048; m += 256) {                          \
        int row = m >> 4, cc = m & 15;                                       \
        uint4 v = *(const uint4*)&Wh[row * 128 + cc * 8];                    \
        *(uint4*)((char*)wlds + row * 256 + ((cc * 16) ^ ((row & 7) << 4))) = v; \
    }

#define MFMA_TILE(acc, tile)                                                 \
    {                                                                        \
        int arow = (tile) * 64 + wave * 16 + lrow;                           \
        bool avalid = arow < N;                                              \
        _Pragma("unroll")                                                    \
        for (int kc = 0; kc < 4; ++kc) {                                     \
            f16x8 a;                                                         \
            if (avalid) a = *(const f16x8*)&Ah[(size_t)arow * 128 + kc * 32 + g * 8]; \
            else        a = (f16x8){0, 0, 0, 0, 0, 0, 0, 0};                 \
            _Pragma("unroll")                                                \
            for (int ct = 0; ct < 8; ++ct) {                                 \
                int row = ct * 16 + lrow;                                    \
                const f16x8 bfr = *(const f16x8*)((const char*)wlds + row * 256 \
                                   + ((kc * 64 + g * 16) ^ ((row & 7) << 4))); \
                acc[ct] = __builtin_amdgcn_mfma_f32_16x16x32_f16(a, bfr, acc[ct], 0, 0, 0); \
            }                                                                \
        }                                                                    \
    }

__global__ void __launch_bounds__(256) k_gemm_stats(const _Float16* __restrict__ Ah,
                                                    const _Float16* __restrict__ Wh,
                                                    const float* __restrict__ bias,
                                                    int N, int ntiles,
                                                    float* __restrict__ partials) {
    __shared__ uint32 wlds[8192];   // 32 KB
    __shared__ float red[1024];
    STAGE_W();
    __syncthreads();

    int t = threadIdx.x;
    int wave = t >> 6, lane = t & 63;
    int lrow = lane & 15, g = lane >> 4;

    float bv[8];
    #pragma unroll
    for (int ct = 0; ct < 8; ++ct) bv[ct] = bias[ct * 16 + lrow];

    float s[8], sq[8];
    #pragma unroll
    for (int ct = 0; ct < 8; ++ct) { s[ct] = 0.f; sq[ct] = 0.f; }

    for (int tile = blockIdx.x; tile < ntiles; tile += gridDim.x) {
        f32x4 acc[8];
        #pragma unroll
        for (int ct = 0; ct < 8; ++ct) acc[ct] = (f32x4){0.f, 0.f, 0.f, 0.f};
        MFMA_TILE(acc, tile);
        int orow0 = tile * 64 + wave * 16 + g * 4;
        #pragma unroll
        for (int ct = 0; ct < 8; ++ct) {
            #pragma unroll
            for (int rr = 0; rr < 4; ++rr) {
                if (orow0 + rr < N) {
                    float o = acc[ct][rr] + bv[ct];
                    s[ct] += o; sq[ct] += o * o;
                }
            }
        }
    }
    #pragma unroll
    for (int ct = 0; ct < 8; ++ct) {
        s[ct] += __shfl_xor(s[ct], 16); sq[ct] += __shfl_xor(sq[ct], 16);
        s[ct] += __shfl_xor(s[ct], 32); sq[ct] += __shfl_xor(sq[ct], 32);
    }
    if (lane < 16) {
        #pragma unroll
        for (int ct = 0; ct < 8; ++ct) {
            int colI = ct * 16 + lrow;
            red[wave * 256 + colI] = s[ct];
            red[wave * 256 + 128 + colI] = sq[ct];
        }
    }
    __syncthreads();
    if (t < 256)
        partials[blockIdx.x * 256 + t] = red[t] + red[256 + t] + red[512 + t] + red[768 + t];
}

// ---------------- BN params: parallel reduction of nblk x 256 partials ----------------

__global__ void __launch_bounds__(1024) k_bnparams(const float* __restrict__ partials, int nblk,
                                                   const float* __restrict__ gamma,
                                                   const float* __restrict__ beta,
                                                   float invN, float* __restrict__ ss) {
    __shared__ float red[1024];
    int tid = threadIdx.x;
    int colI = tid & 255, q = tid >> 8;
    int bq = nblk >> 2;
    float v0 = 0.f, v1 = 0.f, v2 = 0.f, v3 = 0.f;
    int b0 = q * bq;
    for (int b = b0; b < b0 + bq; b += 4) {
        v0 += partials[(b + 0) * 256 + colI];
        v1 += partials[(b + 1) * 256 + colI];
        v2 += partials[(b + 2) * 256 + colI];
        v3 += partials[(b + 3) * 256 + colI];
    }
    red[q * 256 + colI] = (v0 + v1) + (v2 + v3);
    __syncthreads();
    if (tid < 256) {
        float tot = red[tid] + red[256 + tid] + red[512 + tid] + red[768 + tid];
        red[tid] = tot;
    }
    __syncthreads();
    if (tid < 128) {
        float mean = red[tid] * invN;
        float var = red[128 + tid] * invN - mean * mean;
        float sc = gamma[tid] * rsqrtf(var + BN_EPS);
        ss[tid] = sc;
        ss[128 + tid] = beta[tid] - mean * sc;
    }
}

// ---------------- GEMM pass 2: recompute + BN apply + ReLU + residual + store ----------

__global__ void __launch_bounds__(256) k_gemm_apply(const _Float16* __restrict__ Ah,
                                                    const _Float16* __restrict__ Wh,
                                                    const float* __restrict__ bias,
                                                    const float* __restrict__ ss,
                                                    const uint32* __restrict__ xh,
                                                    int N, int ntiles,
                                                    float* __restrict__ out) {
    __shared__ uint32 wlds[8192];   // 32 KB
    STAGE_W();
    __syncthreads();

    int t = threadIdx.x;
    int wave = t >> 6, lane = t & 63;
    int lrow = lane & 15, g = lane >> 4;

    float bv[8], scv[8], shv[8];
    #pragma unroll
    for (int ct = 0; ct < 8; ++ct) {
        int colI = ct * 16 + lrow;
        bv[ct] = bias[colI]; scv[ct] = ss[colI]; shv[ct] = ss[128 + colI];
    }

    for (int tile = blockIdx.x; tile < ntiles; tile += gridDim.x) {
        f32x4 acc[8];
        #pragma unroll
        for (int ct = 0; ct < 8; ++ct) acc[ct] = (f32x4){0.f, 0.f, 0.f, 0.f};
        MFMA_TILE(acc, tile);
        int orow0 = tile * 64 + wave * 16 + g * 4;
        #pragma unroll
        for (int ct = 0; ct < 8; ++ct) {
            int ocol = ct * 16 + lrow;
            #pragma unroll
            for (int rr = 0; rr < 4; ++rr) {
                int r = orow0 + rr;
                if (r < N) {
                    float pre = acc[ct][rr] + bv[ct];
                    float o = fmaxf(pre * scv[ct] + shv[ct], 0.f);
                    uint32 xv = xh[(size_t)r * 64 + (ocol >> 1)];
                    float xr = (ocol & 1) ? h2hi(xv) : h2lo(xv);
                    out[(size_t)r * 128 + ocol] = o + xr;
                }
            }
        }
    }
}

// ---------------- launcher ----------------

extern "C" void kernel_launch(void* const* d_in, const int* in_sizes, int n_in,
                              void* d_out, int out_size, void* d_ws, size_t ws_size,
                              hipStream_t stream) {
    const float* x     = (const float*)d_in[0];
    const int*   ei    = (const int*)d_in[1];
    const float* W     = (const float*)d_in[2];
    const float* bias  = (const float*)d_in[3];
    const float* gamma = (const float*)d_in[4];
    const float* beta  = (const float*)d_in[5];
    float* out = (float*)d_out;

    const int D = 128;
    int N = in_sizes[0] / D;           // requires N <= 256*1024
    int E = in_sizes[1] / 2;
    int NB = (N + 255) >> 8;           // 256-node buckets
    int CAP = ((E + NB - 1) / NB + 1024 + 63) & ~63;

    const int GSTATS = 512;            // 2 blocks/CU for latency hiding
    const int GAPPLY = 512;

    char* ws = (char*)d_ws;
    size_t off = 0;
    auto alloc = [&](size_t bytes) -> void* {
        void* p = ws + off;
        off += (bytes + 255) & ~(size_t)255;
        return p;
    };
    uint32* xh   = (uint32*)alloc((size_t)N * 64 * sizeof(uint32));   // x fp16
    uint32* aggh = (uint32*)alloc((size_t)N * 64 * sizeof(uint32));   // agg fp16
    uint32* bpack= (uint32*)alloc((size_t)NB * CAP * sizeof(uint32));
    int* col     = (int*)alloc((size_t)NB * CAP * sizeof(int));
    _Float16* Wh = (_Float16*)alloc((size_t)D * D * sizeof(_Float16));
    int* rowptr  = (int*)alloc((size_t)N * sizeof(int));
    int* rowcnt  = (int*)alloc((size_t)N * sizeof(int));
    uint32* dpk  = (uint32*)alloc((size_t)N * sizeof(uint32));        // {dinv,dinv} fp16
    float* ss    = (float*)alloc(256 * sizeof(float));
    float* partials = (float*)alloc((size_t)GSTATS * 256 * sizeof(float));
    int* bfill   = (int*)alloc(1024 * sizeof(int));   // zeroed each launch

    hipMemsetAsync(bfill, 0, 1024 * sizeof(int), stream);

    k_prep_scatter<<<2048, 256, 0, stream>>>((const float4*)x, N * 32,
                                             (const float4*)W, D * D / 4,
                                             (uint2*)xh, (uint2*)Wh,
                                             ei, E, NB, CAP, bfill, bpack);
    k_csr<<<NB, 256, 0, stream>>>(bpack, bfill, CAP, N, rowptr, rowcnt, dpk, col);
    k_agg<<<(N + 3) / 4, 256, 0, stream>>>(xh, rowptr, rowcnt, col, dpk, aggh, N);

    int ntiles = (N + 63) / 64;
    k_gemm_stats<<<GSTATS, 256, 0, stream>>>((const _Float16*)aggh, (const _Float16*)Wh,
                                             bias, N, ntiles, partials);
    k_bnparams<<<1, 1024, 0, stream>>>(partials, GSTATS, gamma, beta, 1.0f / (float)N, ss);
    k_gemm_apply<<<GAPPLY, 256, 0, stream>>>((const _Float16*)aggh, (const _Float16*)Wh,
                                             bias, ss, xh, N, ntiles, out);
}

// Round 14
// 175.243 us; speedup vs baseline: 2.3409x; 1.0219x over previous
//
#include <hip/hip_runtime.h>
#include <hip/hip_fp16.h>

#define BN_EPS 1e-5f

typedef unsigned int uint32;
typedef __attribute__((ext_vector_type(8))) _Float16 f16x8;
typedef __attribute__((ext_vector_type(4))) float f32x4;

union H2U { __half2 h; uint32 u; };

__device__ __forceinline__ __half2 u2h(uint32 u) { H2U c; c.u = u; return c.h; }
__device__ __forceinline__ uint32 h2u(__half2 h) { H2U c; c.h = h; return c.u; }
__device__ __forceinline__ uint32 pack2h(float a, float b) {
    return h2u(__halves2half2(__float2half_rn(a), __float2half_rn(b)));
}
__device__ __forceinline__ float h2lo(uint32 u) {
    return __half2float(__ushort_as_half((unsigned short)(u & 0xffffu)));
}
__device__ __forceinline__ float h2hi(uint32 u) {
    return __half2float(__ushort_as_half((unsigned short)(u >> 16)));
}

// ---------------- fused: bucket scatter (blocks 0-255) + fp32->fp16 convert (blocks 256+) ----

__global__ void __launch_bounds__(256) k_prep_scatter(const float4* __restrict__ x4, int nx4,
                                                      const float4* __restrict__ w4, int nw4,
                                                      uint2* __restrict__ xh4, uint2* __restrict__ wh4,
                                                      const int* __restrict__ ei, int E, int NB,
                                                      int CAP, int* __restrict__ bfill,
                                                      uint32* __restrict__ bpack) {
    int t = threadIdx.x;
    if (blockIdx.x < 256) {
        // ---- bucket scatter slice (wave-replicated LDS counters) ----
        __shared__ int h[4][1024];
        int wave = t >> 6;
        int c0 = (int)((long long)blockIdx.x * E / 256);
        int c1 = (int)((long long)(blockIdx.x + 1) * E / 256);
        for (int i = t; i < 4 * 1024; i += 256) h[i >> 10][i & 1023] = 0;
        __syncthreads();
        for (int e = c0 + t; e < c1; e += 256)
            atomicAdd(&h[wave][ei[E + e] >> 8], 1);
        __syncthreads();
        for (int i = t; i < NB; i += 256) {
            int n0 = h[0][i], n1 = h[1][i], n2 = h[2][i], n3 = h[3][i];
            int tot = n0 + n1 + n2 + n3;
            if (tot > 0) {
                int base = i * CAP + atomicAdd(&bfill[i], tot);
                h[0][i] = base;
                h[1][i] = base + n0;
                h[2][i] = base + n0 + n1;
                h[3][i] = base + n0 + n1 + n2;
            }
        }
        __syncthreads();
        for (int e = c0 + t; e < c1; e += 256) {
            int s = ei[e];
            int d = ei[E + e];
            int b = d >> 8;
            int pos = atomicAdd(&h[wave][b], 1);
            bpack[pos] = ((uint32)(d & 255) << 24) | (uint32)s;
        }
    } else {
        // ---- fp32 -> fp16 convert (runs concurrently with scatter) ----
        int nb = gridDim.x - 256;
        int idx = (blockIdx.x - 256) * 256 + t;
        int stride = nb * 256;
        for (int i = idx; i < nx4; i += stride) {
            float4 v = x4[i];
            xh4[i] = make_uint2(pack2h(v.x, v.y), pack2h(v.z, v.w));
        }
        for (int i = idx; i < nw4; i += stride) {
            float4 v = w4[i];
            wh4[i] = make_uint2(pack2h(v.x, v.y), pack2h(v.z, v.w));
        }
    }
}

// ---------------- per-bucket CSR: count, scan, rowptr/rowcnt, dinv(fp16x2), col --------

__global__ void __launch_bounds__(256) k_csr(const uint32* __restrict__ bpack,
                                             const int* __restrict__ bfill, int CAP,
                                             int N,
                                             int* __restrict__ rowptr,
                                             int* __restrict__ rowcnt,
                                             uint32* __restrict__ dpk,
                                             int* __restrict__ col) {
    __shared__ int h[4][256], s[256], cur[4][256];
    int b = blockIdx.x;
    int t = threadIdx.x;
    int wave = t >> 6;
    int e0 = b * CAP, e1 = e0 + bfill[b];
    h[0][t] = 0; h[1][t] = 0; h[2][t] = 0; h[3][t] = 0;
    __syncthreads();
    for (int e = e0 + t; e < e1; e += 256)
        atomicAdd(&h[wave][bpack[e] >> 24], 1);
    __syncthreads();
    int n0 = h[0][t], n1 = h[1][t], n2 = h[2][t], n3 = h[3][t];
    int cnt = n0 + n1 + n2 + n3;
    s[t] = cnt;
    __syncthreads();
    for (int off = 1; off < 256; off <<= 1) {
        int add = (t >= off) ? s[t - off] : 0;
        __syncthreads();
        s[t] += add;
        __syncthreads();
    }
    int excl = s[t] - cnt;
    int node = (b << 8) + t;
    if (node < N) {
        rowptr[node] = e0 + excl;
        rowcnt[node] = cnt;
        float dv = rsqrtf((float)(cnt + 1));
        dpk[node] = pack2h(dv, dv);
    }
    cur[0][t] = e0 + excl;
    cur[1][t] = e0 + excl + n0;
    cur[2][t] = e0 + excl + n0 + n1;
    cur[3][t] = e0 + excl + n0 + n1 + n2;
    __syncthreads();
    for (int e = e0 + t; e < e1; e += 256) {
        uint32 p = bpack[e];
        int pos = atomicAdd(&cur[wave][p >> 24], 1);
        col[pos] = (int)(p & 0xffffffu);
    }
}

// ---------------- aggregation: wave-per-node, 16 edges/iter, 4 gathers in flight --------
// aggx[i] = di*(di*x[i] + sum_j dinv[j]*x[j]) ; ZERO LDS -> max occupancy (latency-bound)
// Measured floor: ~62 us across 4 structures; limited by random-64B-line L2-miss service.

#define EDGE_FMA(vv, ww)                                   \
    acc0 = __hfma2(u2h((vv).x), u2h(ww), acc0);            \
    acc1 = __hfma2(u2h((vv).y), u2h(ww), acc1);            \
    acc2 = __hfma2(u2h((vv).z), u2h(ww), acc2);            \
    acc3 = __hfma2(u2h((vv).w), u2h(ww), acc3);

__global__ void __launch_bounds__(256) k_agg(const uint32* __restrict__ xh,
                                             const int* __restrict__ rowptr,
                                             const int* __restrict__ rowcnt,
                                             const int* __restrict__ col,
                                             const uint32* __restrict__ dpk,
                                             uint32* __restrict__ aggh, int N) {
    int wid = blockIdx.x * 4 + (threadIdx.x >> 6);
    if (wid >= N) return;
    int lane = threadIdx.x & 63;
    int g = lane >> 4, c = lane & 15;

    __half2 z = __float2half2_rn(0.f);
    __half2 acc0 = z, acc1 = z, acc2 = z, acc3 = z;

    int e0 = rowptr[wid];
    int e1 = e0 + rowcnt[wid];
    int e = e0;
    for (; e + 16 <= e1; e += 16) {
        int i0 = e + g, i1 = e + 4 + g, i2 = e + 8 + g, i3 = e + 12 + g;
        int s0 = col[i0], s1 = col[i1], s2 = col[i2], s3 = col[i3];
        uint32 w0 = dpk[s0], w1 = dpk[s1], w2 = dpk[s2], w3 = dpk[s3];
        uint4 v0 = *(const uint4*)&xh[(size_t)s0 * 64 + c * 4];
        uint4 v1 = *(const uint4*)&xh[(size_t)s1 * 64 + c * 4];
        uint4 v2 = *(const uint4*)&xh[(size_t)s2 * 64 + c * 4];
        uint4 v3 = *(const uint4*)&xh[(size_t)s3 * 64 + c * 4];
        EDGE_FMA(v0, w0); EDGE_FMA(v1, w1); EDGE_FMA(v2, w2); EDGE_FMA(v3, w3);
    }
    if (e < e1) {  // masked tail, <=15 edges
        int i0 = e + g, i1 = e + 4 + g, i2 = e + 8 + g, i3 = e + 12 + g;
        int s0 = 0, s1 = 0, s2 = 0, s3 = 0;
        uint32 w0 = 0, w1 = 0, w2 = 0, w3 = 0;
        if (i0 < e1) { s0 = col[i0]; w0 = dpk[s0]; }
        if (i1 < e1) { s1 = col[i1]; w1 = dpk[s1]; }
        if (i2 < e1) { s2 = col[i2]; w2 = dpk[s2]; }
        if (i3 < e1) { s3 = col[i3]; w3 = dpk[s3]; }
        uint4 v0 = *(const uint4*)&xh[(size_t)s0 * 64 + c * 4];
        uint4 v1 = *(const uint4*)&xh[(size_t)s1 * 64 + c * 4];
        uint4 v2 = *(const uint4*)&xh[(size_t)s2 * 64 + c * 4];
        uint4 v3 = *(const uint4*)&xh[(size_t)s3 * 64 + c * 4];
        EDGE_FMA(v0, w0); EDGE_FMA(v1, w1); EDGE_FMA(v2, w2); EDGE_FMA(v3, w3);
    }
    // reduce across the 4 edge-groups (lanes xor 16, 32)
    uint32 u;
    u = __shfl_xor(h2u(acc0), 16); acc0 = __hadd2(acc0, u2h(u));
    u = __shfl_xor(h2u(acc0), 32); acc0 = __hadd2(acc0, u2h(u));
    u = __shfl_xor(h2u(acc1), 16); acc1 = __hadd2(acc1, u2h(u));
    u = __shfl_xor(h2u(acc1), 32); acc1 = __hadd2(acc1, u2h(u));
    u = __shfl_xor(h2u(acc2), 16); acc2 = __hadd2(acc2, u2h(u));
    u = __shfl_xor(h2u(acc2), 32); acc2 = __hadd2(acc2, u2h(u));
    u = __shfl_xor(h2u(acc3), 16); acc3 = __hadd2(acc3, u2h(u));
    u = __shfl_xor(h2u(acc3), 32); acc3 = __hadd2(acc3, u2h(u));

    if (g == 0) {
        float di = h2lo(dpk[wid]);
        uint4 sv = *(const uint4*)&xh[(size_t)wid * 64 + c * 4];
        uint4 o;
        o.x = pack2h(di * (di * h2lo(sv.x) + __low2float(acc0)),
                     di * (di * h2hi(sv.x) + __high2float(acc0)));
        o.y = pack2h(di * (di * h2lo(sv.y) + __low2float(acc1)),
                     di * (di * h2hi(sv.y) + __high2float(acc1)));
        o.z = pack2h(di * (di * h2lo(sv.z) + __low2float(acc2)),
                     di * (di * h2hi(sv.z) + __high2float(acc2)));
        o.w = pack2h(di * (di * h2lo(sv.w) + __low2float(acc3)),
                     di * (di * h2hi(sv.w) + __high2float(acc3)));
        *(uint4*)&aggh[(size_t)wid * 64 + c * 4] = o;
    }
}

// ---------------- persistent MFMA GEMM (fp16), W staged in LDS (XOR-swizzled, 32 KB) ----

#define STAGE_W()                                                            \
    for (int m = threadIdx.x; m < 2048; m += 256) {                          \
        int row = m >> 4, cc = m & 15;                                       \
        uint4 v = *(const uint4*)&Wh[row * 128 + cc * 8];                    \
        *(uint4*)((char*)wlds + row * 256 + ((cc * 16) ^ ((row & 7) << 4))) = v; \
    }

#define MFMA_TILE(acc, tile)                                                 \
    {                                                                        \
        int arow = (tile) * 64 + wave * 16 + lrow;                           \
        bool avalid = arow < N;                                              \
        _Pragma("unroll")                                                    \
        for (int kc = 0; kc < 4; ++kc) {                                     \
            f16x8 a;                                                         \
            if (avalid) a = *(const f16x8*)&Ah[(size_t)arow * 128 + kc * 32 + g * 8]; \
            else        a = (f16x8){0, 0, 0, 0, 0, 0, 0, 0};                 \
            _Pragma("unroll")                                                \
            for (int ct = 0; ct < 8; ++ct) {                                 \
                int row = ct * 16 + lrow;                                    \
                const f16x8 bfr = *(const f16x8*)((const char*)wlds + row * 256 \
                                   + ((kc * 64 + g * 16) ^ ((row & 7) << 4))); \
                acc[ct] = __builtin_amdgcn_mfma_f32_16x16x32_f16(a, bfr, acc[ct], 0, 0, 0); \
            }                                                                \
        }                                                                    \
    }

__global__ void __launch_bounds__(256) k_gemm_stats(const _Float16* __restrict__ Ah,
                                                    const _Float16* __restrict__ Wh,
                                                    const float* __restrict__ bias,
                                                    int N, int ntiles,
                                                    float* __restrict__ partials) {
    __shared__ uint32 wlds[8192];   // 32 KB
    __shared__ float red[1024];
    STAGE_W();
    __syncthreads();

    int t = threadIdx.x;
    int wave = t >> 6, lane = t & 63;
    int lrow = lane & 15, g = lane >> 4;

    float bv[8];
    #pragma unroll
    for (int ct = 0; ct < 8; ++ct) bv[ct] = bias[ct * 16 + lrow];

    float s[8], sq[8];
    #pragma unroll
    for (int ct = 0; ct < 8; ++ct) { s[ct] = 0.f; sq[ct] = 0.f; }

    for (int tile = blockIdx.x; tile < ntiles; tile += gridDim.x) {
        f32x4 acc[8];
        #pragma unroll
        for (int ct = 0; ct < 8; ++ct) acc[ct] = (f32x4){0.f, 0.f, 0.f, 0.f};
        MFMA_TILE(acc, tile);
        int orow0 = tile * 64 + wave * 16 + g * 4;
        #pragma unroll
        for (int ct = 0; ct < 8; ++ct) {
            #pragma unroll
            for (int rr = 0; rr < 4; ++rr) {
                if (orow0 + rr < N) {
                    float o = acc[ct][rr] + bv[ct];
                    s[ct] += o; sq[ct] += o * o;
                }
            }
        }
    }
    #pragma unroll
    for (int ct = 0; ct < 8; ++ct) {
        s[ct] += __shfl_xor(s[ct], 16); sq[ct] += __shfl_xor(sq[ct], 16);
        s[ct] += __shfl_xor(s[ct], 32); sq[ct] += __shfl_xor(sq[ct], 32);
    }
    if (lane < 16) {
        #pragma unroll
        for (int ct = 0; ct < 8; ++ct) {
            int colI = ct * 16 + lrow;
            red[wave * 256 + colI] = s[ct];
            red[wave * 256 + 128 + colI] = sq[ct];
        }
    }
    __syncthreads();
    if (t < 256)
        partials[blockIdx.x * 256 + t] = red[t] + red[256 + t] + red[512 + t] + red[768 + t];
}

// ---------------- BN params: parallel reduction of nblk x 256 partials ----------------

__global__ void __launch_bounds__(1024) k_bnparams(const float* __restrict__ partials, int nblk,
                                                   const float* __restrict__ gamma,
                                                   const float* __restrict__ beta,
                                                   float invN, float* __restrict__ ss) {
    __shared__ float red[1024];
    int tid = threadIdx.x;
    int colI = tid & 255, q = tid >> 8;
    int bq = nblk >> 2;
    float v0 = 0.f, v1 = 0.f, v2 = 0.f, v3 = 0.f;
    int b0 = q * bq;
    for (int b = b0; b < b0 + bq; b += 4) {
        v0 += partials[(b + 0) * 256 + colI];
        v1 += partials[(b + 1) * 256 + colI];
        v2 += partials[(b + 2) * 256 + colI];
        v3 += partials[(b + 3) * 256 + colI];
    }
    red[q * 256 + colI] = (v0 + v1) + (v2 + v3);
    __syncthreads();
    if (tid < 256) {
        float tot = red[tid] + red[256 + tid] + red[512 + tid] + red[768 + tid];
        red[tid] = tot;
    }
    __syncthreads();
    if (tid < 128) {
        float mean = red[tid] * invN;
        float var = red[128 + tid] * invN - mean * mean;
        float sc = gamma[tid] * rsqrtf(var + BN_EPS);
        ss[tid] = sc;
        ss[128 + tid] = beta[tid] - mean * sc;
    }
}

// ---------------- GEMM pass 2: recompute + BN apply + ReLU + residual + store ----------

__global__ void __launch_bounds__(256) k_gemm_apply(const _Float16* __restrict__ Ah,
                                                    const _Float16* __restrict__ Wh,
                                                    const float* __restrict__ bias,
                                                    const float* __restrict__ ss,
                                                    const uint32* __restrict__ xh,
                                                    int N, int ntiles,
                                                    float* __restrict__ out) {
    __shared__ uint32 wlds[8192];   // 32 KB
    STAGE_W();
    __syncthreads();

    int t = threadIdx.x;
    int wave = t >> 6, lane = t & 63;
    int lrow = lane & 15, g = lane >> 4;

    float bv[8], scv[8], shv[8];
    #pragma unroll
    for (int ct = 0; ct < 8; ++ct) {
        int colI = ct * 16 + lrow;
        bv[ct] = bias[colI]; scv[ct] = ss[colI]; shv[ct] = ss[128 + colI];
    }

    for (int tile = blockIdx.x; tile < ntiles; tile += gridDim.x) {
        f32x4 acc[8];
        #pragma unroll
        for (int ct = 0; ct < 8; ++ct) acc[ct] = (f32x4){0.f, 0.f, 0.f, 0.f};
        MFMA_TILE(acc, tile);
        int orow0 = tile * 64 + wave * 16 + g * 4;
        #pragma unroll
        for (int ct = 0; ct < 8; ++ct) {
            int ocol = ct * 16 + lrow;
            #pragma unroll
            for (int rr = 0; rr < 4; ++rr) {
                int r = orow0 + rr;
                if (r < N) {
                    float pre = acc[ct][rr] + bv[ct];
                    float o = fmaxf(pre * scv[ct] + shv[ct], 0.f);
                    uint32 xv = xh[(size_t)r * 64 + (ocol >> 1)];
                    float xr = (ocol & 1) ? h2hi(xv) : h2lo(xv);
                    out[(size_t)r * 128 + ocol] = o + xr;
                }
            }
        }
    }
}

// ---------------- launcher ----------------

extern "C" void kernel_launch(void* const* d_in, const int* in_sizes, int n_in,
                              void* d_out, int out_size, void* d_ws, size_t ws_size,
                              hipStream_t stream) {
    const float* x     = (const float*)d_in[0];
    const int*   ei    = (const int*)d_in[1];
    const float* W     = (const float*)d_in[2];
    const float* bias  = (const float*)d_in[3];
    const float* gamma = (const float*)d_in[4];
    const float* beta  = (const float*)d_in[5];
    float* out = (float*)d_out;

    const int D = 128;
    int N = in_sizes[0] / D;           // requires N <= 256*1024
    int E = in_sizes[1] / 2;
    int NB = (N + 255) >> 8;           // 256-node buckets
    int CAP = ((E + NB - 1) / NB + 1024 + 63) & ~63;

    const int GSTATS = 256;            // measured best (R11): 1 block/CU, MFMA covers latency
    const int GAPPLY = 512;

    char* ws = (char*)d_ws;
    size_t off = 0;
    auto alloc = [&](size_t bytes) -> void* {
        void* p = ws + off;
        off += (bytes + 255) & ~(size_t)255;
        return p;
    };
    uint32* xh   = (uint32*)alloc((size_t)N * 64 * sizeof(uint32));   // x fp16
    uint32* aggh = (uint32*)alloc((size_t)N * 64 * sizeof(uint32));   // agg fp16
    uint32* bpack= (uint32*)alloc((size_t)NB * CAP * sizeof(uint32));
    int* col     = (int*)alloc((size_t)NB * CAP * sizeof(int));
    _Float16* Wh = (_Float16*)alloc((size_t)D * D * sizeof(_Float16));
    int* rowptr  = (int*)alloc((size_t)N * sizeof(int));
    int* rowcnt  = (int*)alloc((size_t)N * sizeof(int));
    uint32* dpk  = (uint32*)alloc((size_t)N * sizeof(uint32));        // {dinv,dinv} fp16
    float* ss    = (float*)alloc(256 * sizeof(float));
    float* partials = (float*)alloc((size_t)GSTATS * 256 * sizeof(float));
    int* bfill   = (int*)alloc(1024 * sizeof(int));   // zeroed each launch

    hipMemsetAsync(bfill, 0, 1024 * sizeof(int), stream);

    k_prep_scatter<<<2048, 256, 0, stream>>>((const float4*)x, N * 32,
                                             (const float4*)W, D * D / 4,
                                             (uint2*)xh, (uint2*)Wh,
                                             ei, E, NB, CAP, bfill, bpack);
    k_csr<<<NB, 256, 0, stream>>>(bpack, bfill, CAP, N, rowptr, rowcnt, dpk, col);
    k_agg<<<(N + 3) / 4, 256, 0, stream>>>(xh, rowptr, rowcnt, col, dpk, aggh, N);

    int ntiles = (N + 63) / 64;
    k_gemm_stats<<<GSTATS, 256, 0, stream>>>((const _Float16*)aggh, (const _Float16*)Wh,
                                             bias, N, ntiles, partials);
    k_bnparams<<<1, 1024, 0, stream>>>(partials, GSTATS, gamma, beta, 1.0f / (float)N, ss);
    k_gemm_apply<<<GAPPLY, 256, 0, stream>>>((const _Float16*)aggh, (const _Float16*)Wh,
                                             bias, ss, xh, N, ntiles, out);
}